// Round 4
// baseline (1130.321 us; speedup 1.0000x reference)
//
#include <hip/hip_runtime.h>

#define DMODEL 1024
#define NHEADS 16
#define HDIM 64
#define DFF 4096
#define WINDOW 128
#define LROWS 2048
#define BATCH 2
#define MROWS (BATCH*LROWS)

typedef __attribute__((ext_vector_type(8))) __bf16 bf16x8;
typedef __attribute__((ext_vector_type(4))) float f32x4;

__device__ inline unsigned short f2bf(float f) {
  union { float f; unsigned int u; } c; c.f = f;
  unsigned int u = c.u;
  unsigned int r = (u + 0x7fffu + ((u >> 16) & 1u)) >> 16;
  return (unsigned short)r;
}
__device__ inline float bf2f(unsigned short s) {
  union { unsigned int u; float f; } c; c.u = ((unsigned int)s) << 16;
  return c.f;
}

// ---------------- transpose + fp32->bf16 convert: out[c][r] = (bf16)in[r][c]
__global__ __launch_bounds__(256)
void transpose_bf16(const float* __restrict__ in, unsigned short* __restrict__ out,
                    int R, int C) {
  __shared__ float tile[32][33];
  const int c0 = blockIdx.x * 32, r0 = blockIdx.y * 32;
  const int tx = threadIdx.x, ty = threadIdx.y;
  #pragma unroll
  for (int r = 0; r < 4; ++r) {
    int rr = ty + r * 8;
    tile[rr][tx] = in[(size_t)(r0 + rr) * C + c0 + tx];
  }
  __syncthreads();
  #pragma unroll
  for (int r = 0; r < 4; ++r) {
    int rr = ty + r * 8;
    out[(size_t)(c0 + rr) * R + r0 + tx] = f2bf(tile[tx][rr]);
  }
}

// ---------------- concat q/k/v biases into one [3072] fp32 vector
__global__ __launch_bounds__(256)
void concat_bias(const float* __restrict__ a, const float* __restrict__ b,
                 const float* __restrict__ c, float* __restrict__ o) {
  const int i = blockIdx.x * 256 + threadIdx.x;
  float v = (i < 1024) ? a[i] : (i < 2048) ? b[i - 1024] : c[i - 2048];
  o[i] = v;
}

// ---------------- LayerNorm (fp32 in, bf16 out), one row (D=1024) per block
__global__ __launch_bounds__(256)
void ln_kernel(const float* __restrict__ x, const float* __restrict__ w,
               const float* __restrict__ b, unsigned short* __restrict__ out) {
  const int row = blockIdx.x;
  const int tid = threadIdx.x;
  const float4 v = *(const float4*)(x + (size_t)row * DMODEL + tid * 4);
  float s = v.x + v.y + v.z + v.w;
  float sq = v.x * v.x + v.y * v.y + v.z * v.z + v.w * v.w;
  #pragma unroll
  for (int off = 32; off; off >>= 1) {
    s += __shfl_xor(s, off);
    sq += __shfl_xor(sq, off);
  }
  __shared__ float rs_[4], rq_[4];
  const int lane = tid & 63, wid = tid >> 6;
  if (lane == 0) { rs_[wid] = s; rq_[wid] = sq; }
  __syncthreads();
  s = rs_[0] + rs_[1] + rs_[2] + rs_[3];
  sq = rq_[0] + rq_[1] + rq_[2] + rq_[3];
  const float mean = s * (1.0f / DMODEL);
  const float var = sq * (1.0f / DMODEL) - mean * mean;
  const float rstd = rsqrtf(var + 1e-5f);
  const float4 wv = *(const float4*)(w + tid * 4);
  const float4 bv = *(const float4*)(b + tid * 4);
  ushort4 o;
  o.x = f2bf((v.x - mean) * rstd * wv.x + bv.x);
  o.y = f2bf((v.y - mean) * rstd * wv.y + bv.y);
  o.z = f2bf((v.z - mean) * rstd * wv.z + bv.z);
  o.w = f2bf((v.w - mean) * rstd * wv.w + bv.w);
  *(ushort4*)(out + (size_t)row * DMODEL + tid * 4) = o;
}

// ---------------- GEMM: C[M][N] = act(A[M][K] @ Bt[N][K]^T + bias) (+resid)
// A, Bt bf16 (ushort bits); acc fp32; 128x128 tile, 4 waves 2x2, 16x16x32 MFMA.
template<int ACT, bool RES, bool OUTBF>
__global__ __launch_bounds__(256)
void gemm_kernel(const unsigned short* __restrict__ A, const unsigned short* __restrict__ Bt,
                 const float* __restrict__ bias, const float* __restrict__ resid,
                 void* __restrict__ outp, int N, int K) {
  __shared__ unsigned short lda[128 * 64];
  __shared__ unsigned short ldb[128 * 64];
  const int tid = threadIdx.x;
  const int lane = tid & 63;
  const int wid = tid >> 6;
  const int wm = (wid >> 1) * 64;
  const int wn = (wid & 1) * 64;
  const int m0 = blockIdx.y * 128;
  const int n0 = blockIdx.x * 128;

  f32x4 acc[4][4];
  #pragma unroll
  for (int mi = 0; mi < 4; ++mi)
    #pragma unroll
    for (int nj = 0; nj < 4; ++nj)
      acc[mi][nj] = (f32x4){0.f, 0.f, 0.f, 0.f};

  for (int kt = 0; kt < K; kt += 64) {
    // stage full 128x64 bf16 tiles: 1024 chunks of 16B per operand
    #pragma unroll
    for (int s2 = 0; s2 < 4; ++s2) {
      const int c = tid + s2 * 256;
      const int row = c >> 3, kc = c & 7;
      const uint4 va = *(const uint4*)(A + (size_t)(m0 + row) * K + kt + kc * 8);
      const uint4 vb = *(const uint4*)(Bt + (size_t)(n0 + row) * K + kt + kc * 8);
      const int off = (row * 128 + kc * 16) ^ ((row & 7) << 4);
      *(uint4*)((char*)lda + off) = va;
      *(uint4*)((char*)ldb + off) = vb;
    }
    __syncthreads();
    #pragma unroll
    for (int kk = 0; kk < 2; ++kk) {
      bf16x8 af[4], bfr[4];
      #pragma unroll
      for (int mi = 0; mi < 4; ++mi) {
        const int row = wm + mi * 16 + (lane & 15);
        const int off = (row * 128 + kk * 64 + (lane >> 4) * 16) ^ ((row & 7) << 4);
        af[mi] = *(const bf16x8*)((const char*)lda + off);
      }
      #pragma unroll
      for (int nj = 0; nj < 4; ++nj) {
        const int row = wn + nj * 16 + (lane & 15);
        const int off = (row * 128 + kk * 64 + (lane >> 4) * 16) ^ ((row & 7) << 4);
        bfr[nj] = *(const bf16x8*)((const char*)ldb + off);
      }
      #pragma unroll
      for (int mi = 0; mi < 4; ++mi)
        #pragma unroll
        for (int nj = 0; nj < 4; ++nj)
          acc[mi][nj] = __builtin_amdgcn_mfma_f32_16x16x32_bf16(af[mi], bfr[nj], acc[mi][nj], 0, 0, 0);
    }
    __syncthreads();
  }

  #pragma unroll
  for (int mi = 0; mi < 4; ++mi) {
    #pragma unroll
    for (int nj = 0; nj < 4; ++nj) {
      const int col = n0 + wn + nj * 16 + (lane & 15);
      const float bc = bias[col];
      const int rbase = m0 + wm + mi * 16 + ((lane >> 4) << 2);
      #pragma unroll
      for (int r = 0; r < 4; ++r) {
        const size_t idx = (size_t)(rbase + r) * N + col;
        float v = acc[mi][nj][r] + bc;
        if (ACT == 1) {
          const float x3 = v * v * v;
          v = 0.5f * v * (1.0f + tanhf(0.7978845608028654f * (v + 0.044715f * x3)));
        }
        if (RES) v += resid[idx];
        if (OUTBF) ((unsigned short*)outp)[idx] = f2bf(v);
        else       ((float*)outp)[idx] = v;
      }
    }
  }
}

// ---------------- sliding-window causal attention, one wave per (b,h,i)
// QKV interleaved [M][3*DMODEL]: q at +0, k at +DMODEL, v at +2*DMODEL
__global__ __launch_bounds__(256)
void attn_kernel(const unsigned short* __restrict__ QKV, unsigned short* __restrict__ O) {
  const int lane = threadIdx.x & 63;
  const int g = blockIdx.x * 4 + (threadIdx.x >> 6);
  const int i = g & (LROWS - 1);
  const int h = (g >> 11) & (NHEADS - 1);
  const int b = g >> 15;
  const size_t rs = 3 * DMODEL;
  const size_t base = (size_t)b * LROWS * rs;
  const size_t hoff = (size_t)h * HDIM + lane;

  const float q = bf2f(QKV[base + (size_t)i * rs + hoff]) * 0.125f;
  int jlo = i - WINDOW; if (jlo < 0) jlo = 0;
  const int nk = i - jlo + 1;

  float s0 = -1e30f, s1 = -1e30f, s2 = -1e30f;
  for (int t = 0; t < nk; ++t) {
    const int j = jlo + t;
    float p = q * bf2f(QKV[base + (size_t)j * rs + DMODEL + hoff]);
    #pragma unroll
    for (int off = 32; off; off >>= 1) p += __shfl_xor(p, off);
    if (lane == (t & 63)) {
      if (t < 64) s0 = p; else if (t < 128) s1 = p; else s2 = p;
    }
  }
  float m = fmaxf(s0, fmaxf(s1, s2));
  #pragma unroll
  for (int off = 32; off; off >>= 1) m = fmaxf(m, __shfl_xor(m, off));
  const float p0 = __expf(s0 - m), p1 = __expf(s1 - m), p2 = __expf(s2 - m);
  float den = p0 + p1 + p2;
  #pragma unroll
  for (int off = 32; off; off >>= 1) den += __shfl_xor(den, off);

  float acc = 0.f;
  for (int t = 0; t < nk; ++t) {
    const int j = jlo + t;
    const float ps = (t < 64) ? p0 : ((t < 128) ? p1 : p2);
    const float pj = __shfl(ps, t & 63);
    acc += pj * bf2f(QKV[base + (size_t)j * rs + 2 * DMODEL + hoff]);
  }
  O[(size_t)b * LROWS * DMODEL + (size_t)i * DMODEL + hoff] = f2bf(acc / den);
}

extern "C" void kernel_launch(void* const* d_in, const int* in_sizes, int n_in,
                              void* d_out, int out_size, void* d_ws, size_t ws_size,
                              hipStream_t stream) {
  const float* x    = (const float*)d_in[0];
  const float* Wq   = (const float*)d_in[1];
  const float* bq   = (const float*)d_in[2];
  const float* Wk   = (const float*)d_in[3];
  const float* bk   = (const float*)d_in[4];
  const float* Wv   = (const float*)d_in[5];
  const float* bv   = (const float*)d_in[6];
  const float* Wo   = (const float*)d_in[7];
  const float* bo   = (const float*)d_in[8];
  const float* W1   = (const float*)d_in[9];
  const float* b1   = (const float*)d_in[10];
  const float* W2   = (const float*)d_in[11];
  const float* b2   = (const float*)d_in[12];
  const float* ln1w = (const float*)d_in[13];
  const float* ln1b = (const float*)d_in[14];
  const float* ln2w = (const float*)d_in[15];
  const float* ln2b = (const float*)d_in[16];

  char* ws = (char*)d_ws;
  const size_t MB = 1024ull * 1024ull;
  // lifetimes: Wqkvt+Wot dead after O-proj -> H2 aliases 0..8MB.
  //            QKV dead after attn, CTX dead after O-proj -> FFN1 aliases 25..57MB.
  unsigned short* Wqkvt = (unsigned short*)(ws + 0 * MB);   // [3072][1024] bf16, 6MB
  unsigned short* Wot   = (unsigned short*)(ws + 6 * MB);   // 2MB
  unsigned short* W1t   = (unsigned short*)(ws + 8 * MB);   // [4096][1024], 8MB
  unsigned short* W2t   = (unsigned short*)(ws + 16 * MB);  // [1024][4096], 8MB
  float*          bqkv  = (float*)(ws + 24 * MB);           // [3072] fp32
  unsigned short* QKV   = (unsigned short*)(ws + 25 * MB);  // [4096][3072] bf16, 24MB
  unsigned short* H1    = (unsigned short*)(ws + 49 * MB);  // [4096][1024], 8MB
  unsigned short* CTX   = (unsigned short*)(ws + 49 * MB);  // aliases H1 (dead)
  unsigned short* H2    = (unsigned short*)(ws + 0 * MB);   // aliases Wqkvt+Wot (dead)
  unsigned short* FFN1  = (unsigned short*)(ws + 25 * MB);  // [4096][4096], 32MB, aliases QKV+CTX

  dim3 tb(32, 8);
  transpose_bf16<<<dim3(32, 32), tb, 0, stream>>>(Wq, Wqkvt, DMODEL, DMODEL);
  transpose_bf16<<<dim3(32, 32), tb, 0, stream>>>(Wk, Wqkvt + 1024 * 1024, DMODEL, DMODEL);
  transpose_bf16<<<dim3(32, 32), tb, 0, stream>>>(Wv, Wqkvt + 2048 * 1024, DMODEL, DMODEL);
  transpose_bf16<<<dim3(32, 32), tb, 0, stream>>>(Wo, Wot, DMODEL, DMODEL);
  transpose_bf16<<<dim3(128, 32), tb, 0, stream>>>(W1, W1t, DMODEL, DFF);
  transpose_bf16<<<dim3(32, 128), tb, 0, stream>>>(W2, W2t, DFF, DMODEL);
  concat_bias<<<12, 256, 0, stream>>>(bq, bk, bv, bqkv);

  ln_kernel<<<MROWS, 256, 0, stream>>>(x, ln1w, ln1b, H1);

  // fused QKV projection: [4096][1024] @ [3072][1024]^T -> [4096][3072]
  gemm_kernel<0, false, true><<<dim3(24, 32), 256, 0, stream>>>(H1, Wqkvt, bqkv, nullptr, QKV, 3 * DMODEL, DMODEL);

  attn_kernel<<<(BATCH * NHEADS * LROWS) / 4, 256, 0, stream>>>(QKV, CTX);

  gemm_kernel<0, true, false><<<dim3(8, 32), 256, 0, stream>>>(CTX, Wot, bo, x, d_out, DMODEL, DMODEL);

  ln_kernel<<<MROWS, 256, 0, stream>>>((const float*)d_out, ln2w, ln2b, H2);

  gemm_kernel<1, false, true><<<dim3(32, 32), 256, 0, stream>>>(H2, W1t, b1, nullptr, FFN1, DFF, DMODEL);

  gemm_kernel<0, true, false><<<dim3(8, 32), 256, 0, stream>>>(FFN1, W2t, b2, (const float*)d_out, d_out, DMODEL, DFF);
}

// Round 6
// 367.676 us; speedup vs baseline: 3.0742x; 3.0742x over previous
//
#include <hip/hip_runtime.h>

#define DMODEL 1024
#define NHEADS 16
#define HDIM 64
#define DFF 4096
#define WINDOW 128
#define LROWS 2048
#define BATCH 2
#define MROWS (BATCH*LROWS)

typedef __attribute__((ext_vector_type(8))) __bf16 bf16x8;
typedef __attribute__((ext_vector_type(4))) float f32x4;

__device__ inline unsigned short f2bf(float f) {
  union { float f; unsigned int u; } c; c.f = f;
  unsigned int u = c.u;
  unsigned int r = (u + 0x7fffu + ((u >> 16) & 1u)) >> 16;
  return (unsigned short)r;
}
__device__ inline float bf2f(unsigned short s) {
  union { unsigned int u; float f; } c; c.u = ((unsigned int)s) << 16;
  return c.f;
}

// ---------------- transpose + fp32->bf16 convert: out[c][r] = (bf16)in[r][c]
__global__ __launch_bounds__(256)
void transpose_bf16(const float* __restrict__ in, unsigned short* __restrict__ out,
                    int R, int C) {
  __shared__ float tile[32][33];
  const int c0 = blockIdx.x * 32, r0 = blockIdx.y * 32;
  const int tx = threadIdx.x, ty = threadIdx.y;
  #pragma unroll
  for (int r = 0; r < 4; ++r) {
    int rr = ty + r * 8;
    tile[rr][tx] = in[(size_t)(r0 + rr) * C + c0 + tx];
  }
  __syncthreads();
  #pragma unroll
  for (int r = 0; r < 4; ++r) {
    int rr = ty + r * 8;
    out[(size_t)(c0 + rr) * R + r0 + tx] = f2bf(tile[tx][rr]);
  }
}

// ---------------- concat q/k/v biases into one [3072] fp32 vector
__global__ __launch_bounds__(256)
void concat_bias(const float* __restrict__ a, const float* __restrict__ b,
                 const float* __restrict__ c, float* __restrict__ o) {
  const int i = blockIdx.x * 256 + threadIdx.x;
  float v = (i < 1024) ? a[i] : (i < 2048) ? b[i - 1024] : c[i - 2048];
  o[i] = v;
}

// ---------------- LayerNorm (fp32 in, bf16 out), one row (D=1024) per block
__global__ __launch_bounds__(256)
void ln_kernel(const float* __restrict__ x, const float* __restrict__ w,
               const float* __restrict__ b, unsigned short* __restrict__ out) {
  const int row = blockIdx.x;
  const int tid = threadIdx.x;
  const float4 v = *(const float4*)(x + (size_t)row * DMODEL + tid * 4);
  float s = v.x + v.y + v.z + v.w;
  float sq = v.x * v.x + v.y * v.y + v.z * v.z + v.w * v.w;
  #pragma unroll
  for (int off = 32; off; off >>= 1) {
    s += __shfl_xor(s, off);
    sq += __shfl_xor(sq, off);
  }
  __shared__ float rs_[4], rq_[4];
  const int lane = tid & 63, wid = tid >> 6;
  if (lane == 0) { rs_[wid] = s; rq_[wid] = sq; }
  __syncthreads();
  s = rs_[0] + rs_[1] + rs_[2] + rs_[3];
  sq = rq_[0] + rq_[1] + rq_[2] + rq_[3];
  const float mean = s * (1.0f / DMODEL);
  const float var = sq * (1.0f / DMODEL) - mean * mean;
  const float rstd = rsqrtf(var + 1e-5f);
  const float4 wv = *(const float4*)(w + tid * 4);
  const float4 bv = *(const float4*)(b + tid * 4);
  ushort4 o;
  o.x = f2bf((v.x - mean) * rstd * wv.x + bv.x);
  o.y = f2bf((v.y - mean) * rstd * wv.y + bv.y);
  o.z = f2bf((v.z - mean) * rstd * wv.z + bv.z);
  o.w = f2bf((v.w - mean) * rstd * wv.w + bv.w);
  *(ushort4*)(out + (size_t)row * DMODEL + tid * 4) = o;
}

// ---------------- GEMM: C[M][N] = act(A[M][K] @ Bt[N][K]^T + bias) (+resid)
template<int ACT, bool RES, bool OUTBF>
__global__ __launch_bounds__(256)
void gemm_kernel(const unsigned short* __restrict__ A, const unsigned short* __restrict__ Bt,
                 const float* __restrict__ bias, const float* __restrict__ resid,
                 void* __restrict__ outp, int N, int K) {
  __shared__ unsigned short lda[128 * 64];
  __shared__ unsigned short ldb[128 * 64];
  const int tid = threadIdx.x;
  const int lane = tid & 63;
  const int wid = tid >> 6;
  const int wm = (wid >> 1) * 64;
  const int wn = (wid & 1) * 64;
  const int m0 = blockIdx.y * 128;
  const int n0 = blockIdx.x * 128;

  f32x4 acc[4][4];
  #pragma unroll
  for (int mi = 0; mi < 4; ++mi)
    #pragma unroll
    for (int nj = 0; nj < 4; ++nj)
      acc[mi][nj] = (f32x4){0.f, 0.f, 0.f, 0.f};

  for (int kt = 0; kt < K; kt += 64) {
    #pragma unroll
    for (int s2 = 0; s2 < 4; ++s2) {
      const int c = tid + s2 * 256;
      const int row = c >> 3, kc = c & 7;
      const uint4 va = *(const uint4*)(A + (size_t)(m0 + row) * K + kt + kc * 8);
      const uint4 vb = *(const uint4*)(Bt + (size_t)(n0 + row) * K + kt + kc * 8);
      const int off = (row * 128 + kc * 16) ^ ((row & 7) << 4);
      *(uint4*)((char*)lda + off) = va;
      *(uint4*)((char*)ldb + off) = vb;
    }
    __syncthreads();
    #pragma unroll
    for (int kk = 0; kk < 2; ++kk) {
      bf16x8 af[4], bfr[4];
      #pragma unroll
      for (int mi = 0; mi < 4; ++mi) {
        const int row = wm + mi * 16 + (lane & 15);
        const int off = (row * 128 + kk * 64 + (lane >> 4) * 16) ^ ((row & 7) << 4);
        af[mi] = *(const bf16x8*)((const char*)lda + off);
      }
      #pragma unroll
      for (int nj = 0; nj < 4; ++nj) {
        const int row = wn + nj * 16 + (lane & 15);
        const int off = (row * 128 + kk * 64 + (lane >> 4) * 16) ^ ((row & 7) << 4);
        bfr[nj] = *(const bf16x8*)((const char*)ldb + off);
      }
      #pragma unroll
      for (int mi = 0; mi < 4; ++mi)
        #pragma unroll
        for (int nj = 0; nj < 4; ++nj)
          acc[mi][nj] = __builtin_amdgcn_mfma_f32_16x16x32_bf16(af[mi], bfr[nj], acc[mi][nj], 0, 0, 0);
    }
    __syncthreads();
  }

  #pragma unroll
  for (int mi = 0; mi < 4; ++mi) {
    #pragma unroll
    for (int nj = 0; nj < 4; ++nj) {
      const int col = n0 + wn + nj * 16 + (lane & 15);
      const float bc = bias[col];
      const int rbase = m0 + wm + mi * 16 + ((lane >> 4) << 2);
      #pragma unroll
      for (int r = 0; r < 4; ++r) {
        const size_t idx = (size_t)(rbase + r) * N + col;
        float v = acc[mi][nj][r] + bc;
        if (ACT == 1) {
          const float x3 = v * v * v;
          v = 0.5f * v * (1.0f + tanhf(0.7978845608028654f * (v + 0.044715f * x3)));
        }
        if (RES) v += resid[idx];
        if (OUTBF) ((unsigned short*)outp)[idx] = f2bf(v);
        else       ((float*)outp)[idx] = v;
      }
    }
  }
}

// ---------------- MFMA sliding-window attention
// Block = 4 waves; wave w handles queries [i0+16w, i0+16w+16) of one (b,h).
// Keys staged for [i0-128, i0+64) = 192 rows. QKV interleaved [M][3072].
// Wave w consumes key chunks [off_w, off_w+160), off_w = min(16w,32), which
// covers its needed window [16w, 16w+144] within the 192 staged rows.
#define KSPAN 192
#define VPITCH 200

__global__ __launch_bounds__(256)
void attn_kernel(const unsigned short* __restrict__ QKV, unsigned short* __restrict__ O) {
  __shared__ __align__(16) unsigned short k_lds[KSPAN * 64];
  __shared__ __align__(16) unsigned short vt_lds[64 * VPITCH];
  const int tid = threadIdx.x;
  const int lane = tid & 63;
  const int w = tid >> 6;
  const int m = lane & 15;
  const int g = lane >> 4;

  const int qb = blockIdx.x & 31;
  const int h  = (blockIdx.x >> 5) & 15;
  const int b  = blockIdx.x >> 9;
  const int i0 = qb * 64;

  const size_t rowp = 3 * DMODEL;
  const size_t base = (size_t)b * LROWS * rowp;

  // ---- stage K (XOR-swizzled rows) and V^T [d][key]
  for (int it = 0; it < 6; ++it) {
    const int c = tid + it * 256;
    const int kk = c >> 3, dc = c & 7;
    int krow = i0 - 128 + kk; krow = krow < 0 ? 0 : krow;
    const unsigned short* src = QKV + base + (size_t)krow * rowp + DMODEL + h * HDIM + dc * 8;
    const uint4 kv = *(const uint4*)src;
    const int koff = (kk * 128 + dc * 16) ^ (((kk >> 1) & 7) << 4);
    *(uint4*)((char*)k_lds + koff) = kv;
    union { uint4 v; unsigned short s[8]; } u; u.v = *(const uint4*)(src + DMODEL);
    #pragma unroll
    for (int j = 0; j < 8; ++j)
      vt_lds[(dc * 8 + j) * VPITCH + kk] = u.s[j];
  }
  __syncthreads();

  // ---- Q fragments (global, 2x16B per lane)
  const int qrow = i0 + 16 * w + m;
  const unsigned short* qptr = QKV + base + (size_t)qrow * rowp + h * HDIM + g * 8;
  const bf16x8 qf0 = *(const bf16x8*)qptr;
  const bf16x8 qf1 = *(const bf16x8*)(qptr + 32);

  const int q_rel = 16 * w + m;
  const int lo128 = 128 - i0;
  const int qlo = lo128 > q_rel ? lo128 : q_rel;
  const int qhi = q_rel + 128;
  const int offw = (w < 2) ? 16 * w : 32;   // wave's key-chunk base

  // ---- QK^T: per 32-key chunk, even-key tile + odd-key tile (zero-shuffle P)
  float sc[5][2][4];
  #pragma unroll
  for (int c5 = 0; c5 < 5; ++c5) {
    const int key0 = offw + c5 * 32;
    f32x4 a0 = {0.f, 0.f, 0.f, 0.f}, a1 = {0.f, 0.f, 0.f, 0.f};
    const int kre = key0 + 2 * m;
    const int sl = (m & 7) << 4;
    const bf16x8 ke0 = *(const bf16x8*)((const char*)k_lds + ((kre * 128 + g * 16) ^ sl));
    const bf16x8 ke1 = *(const bf16x8*)((const char*)k_lds + ((kre * 128 + 64 + g * 16) ^ sl));
    a0 = __builtin_amdgcn_mfma_f32_16x16x32_bf16(ke0, qf0, a0, 0, 0, 0);
    a0 = __builtin_amdgcn_mfma_f32_16x16x32_bf16(ke1, qf1, a0, 0, 0, 0);
    const bf16x8 ko0 = *(const bf16x8*)((const char*)k_lds + (((kre + 1) * 128 + g * 16) ^ sl));
    const bf16x8 ko1 = *(const bf16x8*)((const char*)k_lds + (((kre + 1) * 128 + 64 + g * 16) ^ sl));
    a1 = __builtin_amdgcn_mfma_f32_16x16x32_bf16(ko0, qf0, a1, 0, 0, 0);
    a1 = __builtin_amdgcn_mfma_f32_16x16x32_bf16(ko1, qf1, a1, 0, 0, 0);
    #pragma unroll
    for (int r = 0; r < 4; ++r) {
      const int je = key0 + 8 * g + 2 * r;
      sc[c5][0][r] = (je >= qlo && je <= qhi) ? a0[r] * 0.125f : -1e30f;
      const int jo = je + 1;
      sc[c5][1][r] = (jo >= qlo && jo <= qhi) ? a1[r] * 0.125f : -1e30f;
    }
  }

  // ---- whole-window softmax (reduce across the 4 lane-groups)
  float mx = -1e30f;
  #pragma unroll
  for (int c5 = 0; c5 < 5; ++c5)
    #pragma unroll
    for (int t = 0; t < 2; ++t)
      #pragma unroll
      for (int r = 0; r < 4; ++r) mx = fmaxf(mx, sc[c5][t][r]);
  mx = fmaxf(mx, __shfl_xor(mx, 16));
  mx = fmaxf(mx, __shfl_xor(mx, 32));
  float sum = 0.f;
  #pragma unroll
  for (int c5 = 0; c5 < 5; ++c5)
    #pragma unroll
    for (int t = 0; t < 2; ++t)
      #pragma unroll
      for (int r = 0; r < 4; ++r) {
        const float p = __expf(sc[c5][t][r] - mx);
        sc[c5][t][r] = p;
        sum += p;
      }
  sum += __shfl_xor(sum, 16);
  sum += __shfl_xor(sum, 32);
  const float rden = 1.0f / sum;

  // ---- PV: P packed in-lane (even/odd interleave), V^T frags from LDS
  f32x4 oacc[4];
  #pragma unroll
  for (int dt = 0; dt < 4; ++dt) oacc[dt] = (f32x4){0.f, 0.f, 0.f, 0.f};
  #pragma unroll
  for (int c5 = 0; c5 < 5; ++c5) {
    union { bf16x8 v; unsigned short s[8]; } yu;
    #pragma unroll
    for (int r = 0; r < 4; ++r) {
      yu.s[2 * r]     = f2bf(sc[c5][0][r]);
      yu.s[2 * r + 1] = f2bf(sc[c5][1][r]);
    }
    const int key0 = offw + c5 * 32;
    #pragma unroll
    for (int dt = 0; dt < 4; ++dt) {
      const bf16x8 vf = *(const bf16x8*)(vt_lds + (dt * 16 + m) * VPITCH + key0 + 8 * g);
      oacc[dt] = __builtin_amdgcn_mfma_f32_16x16x32_bf16(vf, yu.v, oacc[dt], 0, 0, 0);
    }
  }

  // ---- write O[q][d] (lane reg r of d-tile dt -> d = dt*16+4g+r, q = m)
  unsigned short* orow = O + (size_t)(b * LROWS + i0 + 16 * w + m) * DMODEL + h * HDIM;
  #pragma unroll
  for (int dt = 0; dt < 4; ++dt)
    #pragma unroll
    for (int r = 0; r < 4; ++r)
      orow[dt * 16 + 4 * g + r] = f2bf(oacc[dt][r] * rden);
}

extern "C" void kernel_launch(void* const* d_in, const int* in_sizes, int n_in,
                              void* d_out, int out_size, void* d_ws, size_t ws_size,
                              hipStream_t stream) {
  const float* x    = (const float*)d_in[0];
  const float* Wq   = (const float*)d_in[1];
  const float* bq   = (const float*)d_in[2];
  const float* Wk   = (const float*)d_in[3];
  const float* bk   = (const float*)d_in[4];
  const float* Wv   = (const float*)d_in[5];
  const float* bv   = (const float*)d_in[6];
  const float* Wo   = (const float*)d_in[7];
  const float* bo   = (const float*)d_in[8];
  const float* W1   = (const float*)d_in[9];
  const float* b1   = (const float*)d_in[10];
  const float* W2   = (const float*)d_in[11];
  const float* b2   = (const float*)d_in[12];
  const float* ln1w = (const float*)d_in[13];
  const float* ln1b = (const float*)d_in[14];
  const float* ln2w = (const float*)d_in[15];
  const float* ln2b = (const float*)d_in[16];

  char* ws = (char*)d_ws;
  const size_t MB = 1024ull * 1024ull;
  unsigned short* Wqkvt = (unsigned short*)(ws + 0 * MB);   // [3072][1024] bf16, 6MB
  unsigned short* Wot   = (unsigned short*)(ws + 6 * MB);   // 2MB
  unsigned short* W1t   = (unsigned short*)(ws + 8 * MB);   // [4096][1024], 8MB
  unsigned short* W2t   = (unsigned short*)(ws + 16 * MB);  // [1024][4096], 8MB
  float*          bqkv  = (float*)(ws + 24 * MB);           // [3072] fp32
  unsigned short* QKV   = (unsigned short*)(ws + 25 * MB);  // [4096][3072] bf16, 24MB
  unsigned short* H1    = (unsigned short*)(ws + 49 * MB);  // [4096][1024], 8MB
  unsigned short* CTX   = (unsigned short*)(ws + 49 * MB);  // aliases H1 (dead)
  unsigned short* H2    = (unsigned short*)(ws + 0 * MB);   // aliases Wqkvt+Wot (dead)
  unsigned short* FFN1  = (unsigned short*)(ws + 25 * MB);  // [4096][4096], 32MB, aliases QKV+CTX

  dim3 tb(32, 8);
  transpose_bf16<<<dim3(32, 32), tb, 0, stream>>>(Wq, Wqkvt, DMODEL, DMODEL);
  transpose_bf16<<<dim3(32, 32), tb, 0, stream>>>(Wk, Wqkvt + 1024 * 1024, DMODEL, DMODEL);
  transpose_bf16<<<dim3(32, 32), tb, 0, stream>>>(Wv, Wqkvt + 2048 * 1024, DMODEL, DMODEL);
  transpose_bf16<<<dim3(32, 32), tb, 0, stream>>>(Wo, Wot, DMODEL, DMODEL);
  transpose_bf16<<<dim3(128, 32), tb, 0, stream>>>(W1, W1t, DMODEL, DFF);
  transpose_bf16<<<dim3(32, 128), tb, 0, stream>>>(W2, W2t, DFF, DMODEL);
  concat_bias<<<12, 256, 0, stream>>>(bq, bk, bv, bqkv);

  ln_kernel<<<MROWS, 256, 0, stream>>>(x, ln1w, ln1b, H1);

  gemm_kernel<0, false, true><<<dim3(24, 32), 256, 0, stream>>>(H1, Wqkvt, bqkv, nullptr, QKV, 3 * DMODEL, DMODEL);

  attn_kernel<<<BATCH * NHEADS * (LROWS / 64), 256, 0, stream>>>(QKV, CTX);

  gemm_kernel<0, true, false><<<dim3(8, 32), 256, 0, stream>>>(CTX, Wot, bo, x, d_out, DMODEL, DMODEL);

  ln_kernel<<<MROWS, 256, 0, stream>>>((const float*)d_out, ln2w, ln2b, H2);

  gemm_kernel<1, false, true><<<dim3(32, 32), 256, 0, stream>>>(H2, W1t, b1, nullptr, FFN1, DFF, DMODEL);

  gemm_kernel<0, true, false><<<dim3(8, 32), 256, 0, stream>>>(FFN1, W2t, b2, (const float*)d_out, d_out, DMODEL, DFF);
}

// Round 9
// 366.683 us; speedup vs baseline: 3.0826x; 1.0027x over previous
//
#include <hip/hip_runtime.h>

#define DMODEL 1024
#define NHEADS 16
#define HDIM 64
#define DFF 4096
#define WINDOW 128
#define LROWS 2048
#define BATCH 2
#define MROWS (BATCH*LROWS)

typedef __attribute__((ext_vector_type(8))) __bf16 bf16x8;
typedef __attribute__((ext_vector_type(4))) float f32x4;

typedef const __attribute__((address_space(1))) void* gp1;
typedef __attribute__((address_space(3))) void* lp3;

__device__ inline unsigned short f2bf(float f) {
  union { float f; unsigned int u; } c; c.f = f;
  unsigned int u = c.u;
  unsigned int r = (u + 0x7fffu + ((u >> 16) & 1u)) >> 16;
  return (unsigned short)r;
}
__device__ inline float bf2f(unsigned short s) {
  union { unsigned int u; float f; } c; c.u = ((unsigned int)s) << 16;
  return c.f;
}

// ---------------- transpose + fp32->bf16 convert: out[c][r] = (bf16)in[r][c]
__global__ __launch_bounds__(256)
void transpose_bf16(const float* __restrict__ in, unsigned short* __restrict__ out,
                    int R, int C) {
  __shared__ float tile[32][33];
  const int c0 = blockIdx.x * 32, r0 = blockIdx.y * 32;
  const int tx = threadIdx.x, ty = threadIdx.y;
  #pragma unroll
  for (int r = 0; r < 4; ++r) {
    int rr = ty + r * 8;
    tile[rr][tx] = in[(size_t)(r0 + rr) * C + c0 + tx];
  }
  __syncthreads();
  #pragma unroll
  for (int r = 0; r < 4; ++r) {
    int rr = ty + r * 8;
    out[(size_t)(c0 + rr) * R + r0 + tx] = f2bf(tile[tx][rr]);
  }
}

// ---------------- concat q/k/v biases into one [3072] fp32 vector
__global__ __launch_bounds__(256)
void concat_bias(const float* __restrict__ a, const float* __restrict__ b,
                 const float* __restrict__ c, float* __restrict__ o) {
  const int i = blockIdx.x * 256 + threadIdx.x;
  float v = (i < 1024) ? a[i] : (i < 2048) ? b[i - 1024] : c[i - 2048];
  o[i] = v;
}

// ---------------- LayerNorm (fp32 in, bf16 out), one row (D=1024) per block
__global__ __launch_bounds__(256)
void ln_kernel(const float* __restrict__ x, const float* __restrict__ w,
               const float* __restrict__ b, unsigned short* __restrict__ out) {
  const int row = blockIdx.x;
  const int tid = threadIdx.x;
  const float4 v = *(const float4*)(x + (size_t)row * DMODEL + tid * 4);
  float s = v.x + v.y + v.z + v.w;
  float sq = v.x * v.x + v.y * v.y + v.z * v.z + v.w * v.w;
  #pragma unroll
  for (int off = 32; off; off >>= 1) {
    s += __shfl_xor(s, off);
    sq += __shfl_xor(sq, off);
  }
  __shared__ float rs_[4], rq_[4];
  const int lane = tid & 63, wid = tid >> 6;
  if (lane == 0) { rs_[wid] = s; rq_[wid] = sq; }
  __syncthreads();
  s = rs_[0] + rs_[1] + rs_[2] + rs_[3];
  sq = rq_[0] + rq_[1] + rq_[2] + rq_[3];
  const float mean = s * (1.0f / DMODEL);
  const float var = sq * (1.0f / DMODEL) - mean * mean;
  const float rstd = rsqrtf(var + 1e-5f);
  const float4 wv = *(const float4*)(w + tid * 4);
  const float4 bv = *(const float4*)(b + tid * 4);
  ushort4 o;
  o.x = f2bf((v.x - mean) * rstd * wv.x + bv.x);
  o.y = f2bf((v.y - mean) * rstd * wv.y + bv.y);
  o.z = f2bf((v.z - mean) * rstd * wv.z + bv.z);
  o.w = f2bf((v.w - mean) * rstd * wv.w + bv.w);
  *(ushort4*)(out + (size_t)row * DMODEL + tid * 4) = o;
}

// ---------------- GEMM: C[M][N] = act(A[M][K] @ Bt[N][K]^T + bias) (+resid)
// Staging: global_load_lds width=16, linear LDS dest, inverse-swizzled global
// source; reads use the same XOR involution (rule 21).
template<int ACT, bool RES, bool OUTBF>
__global__ __launch_bounds__(256)
void gemm_kernel(const unsigned short* __restrict__ A, const unsigned short* __restrict__ Bt,
                 const float* __restrict__ bias, const float* __restrict__ resid,
                 void* __restrict__ outp, int N, int K) {
  __shared__ __align__(16) unsigned short lda[128 * 64];
  __shared__ __align__(16) unsigned short ldb[128 * 64];
  const int tid = threadIdx.x;
  const int lane = tid & 63;
  const int wid = tid >> 6;
  const int wm = (wid >> 1) * 64;
  const int wn = (wid & 1) * 64;
  const int m0 = blockIdx.y * 128;
  const int n0 = blockIdx.x * 128;

  f32x4 acc[4][4];
  #pragma unroll
  for (int mi = 0; mi < 4; ++mi)
    #pragma unroll
    for (int nj = 0; nj < 4; ++nj)
      acc[mi][nj] = (f32x4){0.f, 0.f, 0.f, 0.f};

  // per-lane pre-swizzled global source (row&7 == lane>>3 within each 8-row chunk)
  const int src_inner = ((lane & 7) << 4) ^ ((lane >> 3) << 4);
  const int rbase = wid * 32 + (lane >> 3);
  const char* gA0 = (const char*)(A + (size_t)(m0 + rbase) * K) + src_inner;
  const char* gB0 = (const char*)(Bt + (size_t)(n0 + rbase) * K) + src_inner;
  const size_t rowstep = (size_t)8 * K * 2;

  for (int kt = 0; kt < K; kt += 64) {
    const size_t koff = (size_t)kt * 2;
    #pragma unroll
    for (int r = 0; r < 4; ++r) {
      __builtin_amdgcn_global_load_lds((gp1)(gA0 + r * rowstep + koff),
                                       (lp3)((char*)lda + (wid * 4 + r) * 1024), 16, 0, 0);
      __builtin_amdgcn_global_load_lds((gp1)(gB0 + r * rowstep + koff),
                                       (lp3)((char*)ldb + (wid * 4 + r) * 1024), 16, 0, 0);
    }
    __syncthreads();
    #pragma unroll
    for (int kk = 0; kk < 2; ++kk) {
      bf16x8 af[4], bfr[4];
      #pragma unroll
      for (int mi = 0; mi < 4; ++mi) {
        const int row = wm + mi * 16 + (lane & 15);
        const int off = (row * 128 + kk * 64 + (lane >> 4) * 16) ^ ((row & 7) << 4);
        af[mi] = *(const bf16x8*)((const char*)lda + off);
      }
      #pragma unroll
      for (int nj = 0; nj < 4; ++nj) {
        const int row = wn + nj * 16 + (lane & 15);
        const int off = (row * 128 + kk * 64 + (lane >> 4) * 16) ^ ((row & 7) << 4);
        bfr[nj] = *(const bf16x8*)((const char*)ldb + off);
      }
      #pragma unroll
      for (int mi = 0; mi < 4; ++mi)
        #pragma unroll
        for (int nj = 0; nj < 4; ++nj)
          acc[mi][nj] = __builtin_amdgcn_mfma_f32_16x16x32_bf16(af[mi], bfr[nj], acc[mi][nj], 0, 0, 0);
    }
    __syncthreads();
  }

  #pragma unroll
  for (int mi = 0; mi < 4; ++mi) {
    #pragma unroll
    for (int nj = 0; nj < 4; ++nj) {
      const int col = n0 + wn + nj * 16 + (lane & 15);
      const float bc = bias[col];
      const int rbase2 = m0 + wm + mi * 16 + ((lane >> 4) << 2);
      #pragma unroll
      for (int r = 0; r < 4; ++r) {
        const size_t idx = (size_t)(rbase2 + r) * N + col;
        float v = acc[mi][nj][r] + bc;
        if (ACT == 1) {
          const float x3 = v * v * v;
          v = 0.5f * v * (1.0f + tanhf(0.7978845608028654f * (v + 0.044715f * x3)));
        }
        if (RES) v += resid[idx];
        if (OUTBF) ((unsigned short*)outp)[idx] = f2bf(v);
        else       ((float*)outp)[idx] = v;
      }
    }
  }
}

// ---------------- MFMA sliding-window attention
// Block = 4 waves; wave w handles queries [i0+16w, i0+16w+16) of one (b,h).
// Keys staged for [i0-128, i0+64) = 192 rows. QKV interleaved [M][3072].
// Wave w consumes key chunks [off_w, off_w+160), off_w = min(16w,32), which
// covers its needed window [16w, 16w+144] within the 192 staged rows.
#define KSPAN 192
#define VPITCH 200

__global__ __launch_bounds__(256)
void attn_kernel(const unsigned short* __restrict__ QKV, unsigned short* __restrict__ O) {
  __shared__ __align__(16) unsigned short k_lds[KSPAN * 64];
  __shared__ __align__(16) unsigned short vt_lds[64 * VPITCH];
  const int tid = threadIdx.x;
  const int lane = tid & 63;
  const int w = tid >> 6;
  const int m = lane & 15;
  const int g = lane >> 4;

  const int qb = blockIdx.x & 31;
  const int h  = (blockIdx.x >> 5) & 15;
  const int b  = blockIdx.x >> 9;
  const int i0 = qb * 64;

  const size_t rowp = 3 * DMODEL;
  const size_t base = (size_t)b * LROWS * rowp;

  // ---- stage K (XOR-swizzled rows) and V^T [d][key]
  for (int it = 0; it < 6; ++it) {
    const int c = tid + it * 256;
    const int kk = c >> 3, dc = c & 7;
    int krow = i0 - 128 + kk; krow = krow < 0 ? 0 : krow;
    const unsigned short* src = QKV + base + (size_t)krow * rowp + DMODEL + h * HDIM + dc * 8;
    const uint4 kv = *(const uint4*)src;
    const int koff = (kk * 128 + dc * 16) ^ (((kk >> 1) & 7) << 4);
    *(uint4*)((char*)k_lds + koff) = kv;
    union { uint4 v; unsigned short s[8]; } u; u.v = *(const uint4*)(src + DMODEL);
    #pragma unroll
    for (int j = 0; j < 8; ++j)
      vt_lds[(dc * 8 + j) * VPITCH + kk] = u.s[j];
  }
  __syncthreads();

  // ---- Q fragments (global, 2x16B per lane)
  const int qrow = i0 + 16 * w + m;
  const unsigned short* qptr = QKV + base + (size_t)qrow * rowp + h * HDIM + g * 8;
  const bf16x8 qf0 = *(const bf16x8*)qptr;
  const bf16x8 qf1 = *(const bf16x8*)(qptr + 32);

  const int q_rel = 16 * w + m;
  const int lo128 = 128 - i0;
  const int qlo = lo128 > q_rel ? lo128 : q_rel;
  const int qhi = q_rel + 128;
  const int offw = (w < 2) ? 16 * w : 32;   // wave's key-chunk base

  // ---- QK^T: per 32-key chunk, even-key tile + odd-key tile (zero-shuffle P)
  float sc[5][2][4];
  #pragma unroll
  for (int c5 = 0; c5 < 5; ++c5) {
    const int key0 = offw + c5 * 32;
    f32x4 a0 = {0.f, 0.f, 0.f, 0.f}, a1 = {0.f, 0.f, 0.f, 0.f};
    const int kre = key0 + 2 * m;
    const int sl = (m & 7) << 4;
    const bf16x8 ke0 = *(const bf16x8*)((const char*)k_lds + ((kre * 128 + g * 16) ^ sl));
    const bf16x8 ke1 = *(const bf16x8*)((const char*)k_lds + ((kre * 128 + 64 + g * 16) ^ sl));
    a0 = __builtin_amdgcn_mfma_f32_16x16x32_bf16(ke0, qf0, a0, 0, 0, 0);
    a0 = __builtin_amdgcn_mfma_f32_16x16x32_bf16(ke1, qf1, a0, 0, 0, 0);
    const bf16x8 ko0 = *(const bf16x8*)((const char*)k_lds + (((kre + 1) * 128 + g * 16) ^ sl));
    const bf16x8 ko1 = *(const bf16x8*)((const char*)k_lds + (((kre + 1) * 128 + 64 + g * 16) ^ sl));
    a1 = __builtin_amdgcn_mfma_f32_16x16x32_bf16(ko0, qf0, a1, 0, 0, 0);
    a1 = __builtin_amdgcn_mfma_f32_16x16x32_bf16(ko1, qf1, a1, 0, 0, 0);
    #pragma unroll
    for (int r = 0; r < 4; ++r) {
      const int je = key0 + 8 * g + 2 * r;
      sc[c5][0][r] = (je >= qlo && je <= qhi) ? a0[r] * 0.125f : -1e30f;
      const int jo = je + 1;
      sc[c5][1][r] = (jo >= qlo && jo <= qhi) ? a1[r] * 0.125f : -1e30f;
    }
  }

  // ---- whole-window softmax (reduce across the 4 lane-groups)
  float mx = -1e30f;
  #pragma unroll
  for (int c5 = 0; c5 < 5; ++c5)
    #pragma unroll
    for (int t = 0; t < 2; ++t)
      #pragma unroll
      for (int r = 0; r < 4; ++r) mx = fmaxf(mx, sc[c5][t][r]);
  mx = fmaxf(mx, __shfl_xor(mx, 16));
  mx = fmaxf(mx, __shfl_xor(mx, 32));
  float sum = 0.f;
  #pragma unroll
  for (int c5 = 0; c5 < 5; ++c5)
    #pragma unroll
    for (int t = 0; t < 2; ++t)
      #pragma unroll
      for (int r = 0; r < 4; ++r) {
        const float p = __expf(sc[c5][t][r] - mx);
        sc[c5][t][r] = p;
        sum += p;
      }
  sum += __shfl_xor(sum, 16);
  sum += __shfl_xor(sum, 32);
  const float rden = 1.0f / sum;

  // ---- PV: P packed in-lane (even/odd interleave), V^T frags from LDS
  f32x4 oacc[4];
  #pragma unroll
  for (int dt = 0; dt < 4; ++dt) oacc[dt] = (f32x4){0.f, 0.f, 0.f, 0.f};
  #pragma unroll
  for (int c5 = 0; c5 < 5; ++c5) {
    union { bf16x8 v; unsigned short s[8]; } yu;
    #pragma unroll
    for (int r = 0; r < 4; ++r) {
      yu.s[2 * r]     = f2bf(sc[c5][0][r]);
      yu.s[2 * r + 1] = f2bf(sc[c5][1][r]);
    }
    const int key0 = offw + c5 * 32;
    #pragma unroll
    for (int dt = 0; dt < 4; ++dt) {
      const bf16x8 vf = *(const bf16x8*)(vt_lds + (dt * 16 + m) * VPITCH + key0 + 8 * g);
      oacc[dt] = __builtin_amdgcn_mfma_f32_16x16x32_bf16(vf, yu.v, oacc[dt], 0, 0, 0);
    }
  }

  // ---- write O[q][d] (lane reg r of d-tile dt -> d = dt*16+4g+r, q = m)
  unsigned short* orow = O + (size_t)(b * LROWS + i0 + 16 * w + m) * DMODEL + h * HDIM;
  #pragma unroll
  for (int dt = 0; dt < 4; ++dt)
    #pragma unroll
    for (int r = 0; r < 4; ++r)
      orow[dt * 16 + 4 * g + r] = f2bf(oacc[dt][r] * rden);
}

extern "C" void kernel_launch(void* const* d_in, const int* in_sizes, int n_in,
                              void* d_out, int out_size, void* d_ws, size_t ws_size,
                              hipStream_t stream) {
  const float* x    = (const float*)d_in[0];
  const float* Wq   = (const float*)d_in[1];
  const float* bq   = (const float*)d_in[2];
  const float* Wk   = (const float*)d_in[3];
  const float* bk   = (const float*)d_in[4];
  const float* Wv   = (const float*)d_in[5];
  const float* bv   = (const float*)d_in[6];
  const float* Wo   = (const float*)d_in[7];
  const float* bo   = (const float*)d_in[8];
  const float* W1   = (const float*)d_in[9];
  const float* b1   = (const float*)d_in[10];
  const float* W2   = (const float*)d_in[11];
  const float* b2   = (const float*)d_in[12];
  const float* ln1w = (const float*)d_in[13];
  const float* ln1b = (const float*)d_in[14];
  const float* ln2w = (const float*)d_in[15];
  const float* ln2b = (const float*)d_in[16];

  char* ws = (char*)d_ws;
  const size_t MB = 1024ull * 1024ull;
  unsigned short* Wqkvt = (unsigned short*)(ws + 0 * MB);   // [3072][1024] bf16, 6MB
  unsigned short* Wot   = (unsigned short*)(ws + 6 * MB);   // 2MB
  unsigned short* W1t   = (unsigned short*)(ws + 8 * MB);   // [4096][1024], 8MB
  unsigned short* W2t   = (unsigned short*)(ws + 16 * MB);  // [1024][4096], 8MB
  float*          bqkv  = (float*)(ws + 24 * MB);           // [3072] fp32
  unsigned short* QKV   = (unsigned short*)(ws + 25 * MB);  // [4096][3072] bf16, 24MB
  unsigned short* H1    = (unsigned short*)(ws + 49 * MB);  // [4096][1024], 8MB
  unsigned short* CTX   = (unsigned short*)(ws + 49 * MB);  // aliases H1 (dead)
  unsigned short* H2    = (unsigned short*)(ws + 0 * MB);   // aliases Wqkvt+Wot (dead)
  unsigned short* FFN1  = (unsigned short*)(ws + 25 * MB);  // [4096][4096], 32MB, aliases QKV+CTX

  dim3 tb(32, 8);
  transpose_bf16<<<dim3(32, 32), tb, 0, stream>>>(Wq, Wqkvt, DMODEL, DMODEL);
  transpose_bf16<<<dim3(32, 32), tb, 0, stream>>>(Wk, Wqkvt + 1024 * 1024, DMODEL, DMODEL);
  transpose_bf16<<<dim3(32, 32), tb, 0, stream>>>(Wv, Wqkvt + 2048 * 1024, DMODEL, DMODEL);
  transpose_bf16<<<dim3(32, 32), tb, 0, stream>>>(Wo, Wot, DMODEL, DMODEL);
  transpose_bf16<<<dim3(128, 32), tb, 0, stream>>>(W1, W1t, DMODEL, DFF);
  transpose_bf16<<<dim3(32, 128), tb, 0, stream>>>(W2, W2t, DFF, DMODEL);
  concat_bias<<<12, 256, 0, stream>>>(bq, bk, bv, bqkv);

  ln_kernel<<<MROWS, 256, 0, stream>>>(x, ln1w, ln1b, H1);

  gemm_kernel<0, false, true><<<dim3(24, 32), 256, 0, stream>>>(H1, Wqkvt, bqkv, nullptr, QKV, 3 * DMODEL, DMODEL);

  attn_kernel<<<BATCH * NHEADS * (LROWS / 64), 256, 0, stream>>>(QKV, CTX);

  gemm_kernel<0, true, false><<<dim3(8, 32), 256, 0, stream>>>(CTX, Wot, bo, x, d_out, DMODEL, DMODEL);

  ln_kernel<<<MROWS, 256, 0, stream>>>((const float*)d_out, ln2w, ln2b, H2);

  gemm_kernel<1, false, true><<<dim3(32, 32), 256, 0, stream>>>(H2, W1t, b1, nullptr, FFN1, DFF, DMODEL);

  gemm_kernel<0, true, false><<<dim3(8, 32), 256, 0, stream>>>(FFN1, W2t, b2, (const float*)d_out, d_out, DMODEL, DFF);
}

// Round 11
// 336.750 us; speedup vs baseline: 3.3566x; 1.0889x over previous
//
#include <hip/hip_runtime.h>

#define DMODEL 1024
#define NHEADS 16
#define HDIM 64
#define DFF 4096
#define WINDOW 128
#define LROWS 2048
#define BATCH 2
#define MROWS (BATCH*LROWS)

typedef __attribute__((ext_vector_type(8))) __bf16 bf16x8;
typedef __attribute__((ext_vector_type(4))) float f32x4;

typedef const __attribute__((address_space(1))) void* gp1;
typedef __attribute__((address_space(3))) void* lp3;

__device__ inline unsigned short f2bf(float f) {
  union { float f; unsigned int u; } c; c.f = f;
  unsigned int u = c.u;
  unsigned int r = (u + 0x7fffu + ((u >> 16) & 1u)) >> 16;
  return (unsigned short)r;
}
__device__ inline float bf2f(unsigned short s) {
  union { unsigned int u; float f; } c; c.u = ((unsigned int)s) << 16;
  return c.f;
}

// ---------------- transpose + fp32->bf16 convert: out[c][r] = (bf16)in[r][c]
__global__ __launch_bounds__(256)
void transpose_bf16(const float* __restrict__ in, unsigned short* __restrict__ out,
                    int R, int C) {
  __shared__ float tile[32][33];
  const int c0 = blockIdx.x * 32, r0 = blockIdx.y * 32;
  const int tx = threadIdx.x, ty = threadIdx.y;
  #pragma unroll
  for (int r = 0; r < 4; ++r) {
    int rr = ty + r * 8;
    tile[rr][tx] = in[(size_t)(r0 + rr) * C + c0 + tx];
  }
  __syncthreads();
  #pragma unroll
  for (int r = 0; r < 4; ++r) {
    int rr = ty + r * 8;
    out[(size_t)(c0 + rr) * R + r0 + tx] = f2bf(tile[tx][rr]);
  }
}

// ---------------- concat q/k/v biases into one [3072] fp32 vector
__global__ __launch_bounds__(256)
void concat_bias(const float* __restrict__ a, const float* __restrict__ b,
                 const float* __restrict__ c, float* __restrict__ o) {
  const int i = blockIdx.x * 256 + threadIdx.x;
  float v = (i < 1024) ? a[i] : (i < 2048) ? b[i - 1024] : c[i - 2048];
  o[i] = v;
}

// ---------------- LayerNorm (fp32 in, bf16 out), one row (D=1024) per block
__global__ __launch_bounds__(256)
void ln_kernel(const float* __restrict__ x, const float* __restrict__ w,
               const float* __restrict__ b, unsigned short* __restrict__ out) {
  const int row = blockIdx.x;
  const int tid = threadIdx.x;
  const float4 v = *(const float4*)(x + (size_t)row * DMODEL + tid * 4);
  float s = v.x + v.y + v.z + v.w;
  float sq = v.x * v.x + v.y * v.y + v.z * v.z + v.w * v.w;
  #pragma unroll
  for (int off = 32; off; off >>= 1) {
    s += __shfl_xor(s, off);
    sq += __shfl_xor(sq, off);
  }
  __shared__ float rs_[4], rq_[4];
  const int lane = tid & 63, wid = tid >> 6;
  if (lane == 0) { rs_[wid] = s; rq_[wid] = sq; }
  __syncthreads();
  s = rs_[0] + rs_[1] + rs_[2] + rs_[3];
  sq = rq_[0] + rq_[1] + rq_[2] + rq_[3];
  const float mean = s * (1.0f / DMODEL);
  const float var = sq * (1.0f / DMODEL) - mean * mean;
  const float rstd = rsqrtf(var + 1e-5f);
  const float4 wv = *(const float4*)(w + tid * 4);
  const float4 bv = *(const float4*)(b + tid * 4);
  ushort4 o;
  o.x = f2bf((v.x - mean) * rstd * wv.x + bv.x);
  o.y = f2bf((v.y - mean) * rstd * wv.y + bv.y);
  o.z = f2bf((v.z - mean) * rstd * wv.z + bv.z);
  o.w = f2bf((v.w - mean) * rstd * wv.w + bv.w);
  *(ushort4*)(out + (size_t)row * DMODEL + tid * 4) = o;
}

// ---------------- GEMM: C[M][N] = act(A[M][K] @ Bt[N][K]^T + bias) (+resid)
// BM in {64,128}, BN=128, BK=64. Double-buffered LDS, ONE barrier per K-step:
// stage(next) issued BEFORE compute(cur), so the pre-barrier vmcnt(0) drain
// overlaps with the MFMA phase (2-phase pipeline). global_load_lds width=16,
// linear LDS dest, inverse-swizzled global source (rule 21).
template<int BM, int ACT, bool RES, bool OUTBF>
__global__ __launch_bounds__(256)
void gemm_kernel(const unsigned short* __restrict__ A, const unsigned short* __restrict__ Bt,
                 const float* __restrict__ bias, const float* __restrict__ resid,
                 void* __restrict__ outp, int N, int K) {
  constexpr int MI = BM / 32;   // acc m-fragments per wave
  constexpr int RA = BM / 32;   // global_load_lds issues per wave for A
  __shared__ __align__(16) unsigned short lda[2][BM * 64];
  __shared__ __align__(16) unsigned short ldb[2][128 * 64];
  const int tid = threadIdx.x;
  const int lane = tid & 63;
  const int wid = tid >> 6;
  const int wm = (wid >> 1) * (BM / 2);
  const int wn = (wid & 1) * 64;
  const int m0 = blockIdx.y * BM;
  const int n0 = blockIdx.x * 128;

  f32x4 acc[MI][4];
  #pragma unroll
  for (int mi = 0; mi < MI; ++mi)
    #pragma unroll
    for (int nj = 0; nj < 4; ++nj)
      acc[mi][nj] = (f32x4){0.f, 0.f, 0.f, 0.f};

  // per-lane pre-swizzled global source (row&7 == lane>>3 within each 8-row chunk)
  const int src_inner = ((lane & 7) << 4) ^ ((lane >> 3) << 4);
  const int rbaseA = wid * (BM / 4) + (lane >> 3);
  const int rbaseB = wid * 32 + (lane >> 3);
  const char* gA0 = (const char*)(A + (size_t)(m0 + rbaseA) * K) + src_inner;
  const char* gB0 = (const char*)(Bt + (size_t)(n0 + rbaseB) * K) + src_inner;
  const size_t rowstep = (size_t)8 * K * 2;

  auto stage = [&](int buf, int kt) {
    const size_t koff = (size_t)kt * 2;
    #pragma unroll
    for (int r = 0; r < RA; ++r)
      __builtin_amdgcn_global_load_lds((gp1)(gA0 + r * rowstep + koff),
                                       (lp3)((char*)lda[buf] + (wid * RA + r) * 1024), 16, 0, 0);
    #pragma unroll
    for (int r = 0; r < 4; ++r)
      __builtin_amdgcn_global_load_lds((gp1)(gB0 + r * rowstep + koff),
                                       (lp3)((char*)ldb[buf] + (wid * 4 + r) * 1024), 16, 0, 0);
  };

  stage(0, 0);
  __syncthreads();
  int cur = 0;
  for (int kt = 0; kt < K; kt += 64) {
    if (kt + 64 < K) stage(cur ^ 1, kt + 64);   // prefetch flies under the MFMAs
    #pragma unroll
    for (int kk = 0; kk < 2; ++kk) {
      bf16x8 af[MI], bfr[4];
      #pragma unroll
      for (int mi = 0; mi < MI; ++mi) {
        const int row = wm + mi * 16 + (lane & 15);
        const int off = (row * 128 + kk * 64 + (lane >> 4) * 16) ^ ((row & 7) << 4);
        af[mi] = *(const bf16x8*)((const char*)lda[cur] + off);
      }
      #pragma unroll
      for (int nj = 0; nj < 4; ++nj) {
        const int row = wn + nj * 16 + (lane & 15);
        const int off = (row * 128 + kk * 64 + (lane >> 4) * 16) ^ ((row & 7) << 4);
        bfr[nj] = *(const bf16x8*)((const char*)ldb[cur] + off);
      }
      #pragma unroll
      for (int mi = 0; mi < MI; ++mi)
        #pragma unroll
        for (int nj = 0; nj < 4; ++nj)
          acc[mi][nj] = __builtin_amdgcn_mfma_f32_16x16x32_bf16(af[mi], bfr[nj], acc[mi][nj], 0, 0, 0);
    }
    __syncthreads();   // all waves done reading cur; prefetch (issued pre-compute) drained
    cur ^= 1;
  }

  #pragma unroll
  for (int mi = 0; mi < MI; ++mi) {
    #pragma unroll
    for (int nj = 0; nj < 4; ++nj) {
      const int col = n0 + wn + nj * 16 + (lane & 15);
      const float bc = bias[col];
      const int rbase2 = m0 + wm + mi * 16 + ((lane >> 4) << 2);
      #pragma unroll
      for (int r = 0; r < 4; ++r) {
        const size_t idx = (size_t)(rbase2 + r) * N + col;
        float v = acc[mi][nj][r] + bc;
        if (ACT == 1) {
          const float x3 = v * v * v;
          v = 0.5f * v * (1.0f + tanhf(0.7978845608028654f * (v + 0.044715f * x3)));
        }
        if (RES) v += resid[idx];
        if (OUTBF) ((unsigned short*)outp)[idx] = f2bf(v);
        else       ((float*)outp)[idx] = v;
      }
    }
  }
}

// ---------------- MFMA sliding-window attention
// Block = 4 waves; wave w handles queries [i0+16w, i0+16w+16) of one (b,h).
// Keys staged for [i0-128, i0+64) = 192 rows. QKV interleaved [M][3072].
// Wave w consumes key chunks [off_w, off_w+160), off_w = min(16w,32), which
// covers its needed window [16w, 16w+144] within the 192 staged rows.
#define KSPAN 192
#define VPITCH 200

__global__ __launch_bounds__(256)
void attn_kernel(const unsigned short* __restrict__ QKV, unsigned short* __restrict__ O) {
  __shared__ __align__(16) unsigned short k_lds[KSPAN * 64];
  __shared__ __align__(16) unsigned short vt_lds[64 * VPITCH];
  const int tid = threadIdx.x;
  const int lane = tid & 63;
  const int w = tid >> 6;
  const int m = lane & 15;
  const int g = lane >> 4;

  const int qb = blockIdx.x & 31;
  const int h  = (blockIdx.x >> 5) & 15;
  const int b  = blockIdx.x >> 9;
  const int i0 = qb * 64;

  const size_t rowp = 3 * DMODEL;
  const size_t base = (size_t)b * LROWS * rowp;

  // ---- stage K (XOR-swizzled rows) and V^T [d][key]
  for (int it = 0; it < 6; ++it) {
    const int c = tid + it * 256;
    const int kk = c >> 3, dc = c & 7;
    int krow = i0 - 128 + kk; krow = krow < 0 ? 0 : krow;
    const unsigned short* src = QKV + base + (size_t)krow * rowp + DMODEL + h * HDIM + dc * 8;
    const uint4 kv = *(const uint4*)src;
    const int koff = (kk * 128 + dc * 16) ^ (((kk >> 1) & 7) << 4);
    *(uint4*)((char*)k_lds + koff) = kv;
    union { uint4 v; unsigned short s[8]; } u; u.v = *(const uint4*)(src + DMODEL);
    #pragma unroll
    for (int j = 0; j < 8; ++j)
      vt_lds[(dc * 8 + j) * VPITCH + kk] = u.s[j];
  }
  __syncthreads();

  // ---- Q fragments (global, 2x16B per lane)
  const int qrow = i0 + 16 * w + m;
  const unsigned short* qptr = QKV + base + (size_t)qrow * rowp + h * HDIM + g * 8;
  const bf16x8 qf0 = *(const bf16x8*)qptr;
  const bf16x8 qf1 = *(const bf16x8*)(qptr + 32);

  const int q_rel = 16 * w + m;
  const int lo128 = 128 - i0;
  const int qlo = lo128 > q_rel ? lo128 : q_rel;
  const int qhi = q_rel + 128;
  const int offw = (w < 2) ? 16 * w : 32;   // wave's key-chunk base

  // ---- QK^T: per 32-key chunk, even-key tile + odd-key tile (zero-shuffle P)
  float sc[5][2][4];
  #pragma unroll
  for (int c5 = 0; c5 < 5; ++c5) {
    const int key0 = offw + c5 * 32;
    f32x4 a0 = {0.f, 0.f, 0.f, 0.f}, a1 = {0.f, 0.f, 0.f, 0.f};
    const int kre = key0 + 2 * m;
    const int sl = (m & 7) << 4;
    const bf16x8 ke0 = *(const bf16x8*)((const char*)k_lds + ((kre * 128 + g * 16) ^ sl));
    const bf16x8 ke1 = *(const bf16x8*)((const char*)k_lds + ((kre * 128 + 64 + g * 16) ^ sl));
    a0 = __builtin_amdgcn_mfma_f32_16x16x32_bf16(ke0, qf0, a0, 0, 0, 0);
    a0 = __builtin_amdgcn_mfma_f32_16x16x32_bf16(ke1, qf1, a0, 0, 0, 0);
    const bf16x8 ko0 = *(const bf16x8*)((const char*)k_lds + (((kre + 1) * 128 + g * 16) ^ sl));
    const bf16x8 ko1 = *(const bf16x8*)((const char*)k_lds + (((kre + 1) * 128 + 64 + g * 16) ^ sl));
    a1 = __builtin_amdgcn_mfma_f32_16x16x32_bf16(ko0, qf0, a1, 0, 0, 0);
    a1 = __builtin_amdgcn_mfma_f32_16x16x32_bf16(ko1, qf1, a1, 0, 0, 0);
    #pragma unroll
    for (int r = 0; r < 4; ++r) {
      const int je = key0 + 8 * g + 2 * r;
      sc[c5][0][r] = (je >= qlo && je <= qhi) ? a0[r] * 0.125f : -1e30f;
      const int jo = je + 1;
      sc[c5][1][r] = (jo >= qlo && jo <= qhi) ? a1[r] * 0.125f : -1e30f;
    }
  }

  // ---- whole-window softmax (reduce across the 4 lane-groups)
  float mx = -1e30f;
  #pragma unroll
  for (int c5 = 0; c5 < 5; ++c5)
    #pragma unroll
    for (int t = 0; t < 2; ++t)
      #pragma unroll
      for (int r = 0; r < 4; ++r) mx = fmaxf(mx, sc[c5][t][r]);
  mx = fmaxf(mx, __shfl_xor(mx, 16));
  mx = fmaxf(mx, __shfl_xor(mx, 32));
  float sum = 0.f;
  #pragma unroll
  for (int c5 = 0; c5 < 5; ++c5)
    #pragma unroll
    for (int t = 0; t < 2; ++t)
      #pragma unroll
      for (int r = 0; r < 4; ++r) {
        const float p = __expf(sc[c5][t][r] - mx);
        sc[c5][t][r] = p;
        sum += p;
      }
  sum += __shfl_xor(sum, 16);
  sum += __shfl_xor(sum, 32);
  const float rden = 1.0f / sum;

  // ---- PV: P packed in-lane (even/odd interleave), V^T frags from LDS
  f32x4 oacc[4];
  #pragma unroll
  for (int dt = 0; dt < 4; ++dt) oacc[dt] = (f32x4){0.f, 0.f, 0.f, 0.f};
  #pragma unroll
  for (int c5 = 0; c5 < 5; ++c5) {
    union { bf16x8 v; unsigned short s[8]; } yu;
    #pragma unroll
    for (int r = 0; r < 4; ++r) {
      yu.s[2 * r]     = f2bf(sc[c5][0][r]);
      yu.s[2 * r + 1] = f2bf(sc[c5][1][r]);
    }
    const int key0 = offw + c5 * 32;
    #pragma unroll
    for (int dt = 0; dt < 4; ++dt) {
      const bf16x8 vf = *(const bf16x8*)(vt_lds + (dt * 16 + m) * VPITCH + key0 + 8 * g);
      oacc[dt] = __builtin_amdgcn_mfma_f32_16x16x32_bf16(vf, yu.v, oacc[dt], 0, 0, 0);
    }
  }

  // ---- write O[q][d] (lane reg r of d-tile dt -> d = dt*16+4g+r, q = m)
  unsigned short* orow = O + (size_t)(b * LROWS + i0 + 16 * w + m) * DMODEL + h * HDIM;
  #pragma unroll
  for (int dt = 0; dt < 4; ++dt)
    #pragma unroll
    for (int r = 0; r < 4; ++r)
      orow[dt * 16 + 4 * g + r] = f2bf(oacc[dt][r] * rden);
}

extern "C" void kernel_launch(void* const* d_in, const int* in_sizes, int n_in,
                              void* d_out, int out_size, void* d_ws, size_t ws_size,
                              hipStream_t stream) {
  const float* x    = (const float*)d_in[0];
  const float* Wq   = (const float*)d_in[1];
  const float* bq   = (const float*)d_in[2];
  const float* Wk   = (const float*)d_in[3];
  const float* bk   = (const float*)d_in[4];
  const float* Wv   = (const float*)d_in[5];
  const float* bv   = (const float*)d_in[6];
  const float* Wo   = (const float*)d_in[7];
  const float* bo   = (const float*)d_in[8];
  const float* W1   = (const float*)d_in[9];
  const float* b1   = (const float*)d_in[10];
  const float* W2   = (const float*)d_in[11];
  const float* b2   = (const float*)d_in[12];
  const float* ln1w = (const float*)d_in[13];
  const float* ln1b = (const float*)d_in[14];
  const float* ln2w = (const float*)d_in[15];
  const float* ln2b = (const float*)d_in[16];

  char* ws = (char*)d_ws;
  const size_t MB = 1024ull * 1024ull;
  unsigned short* Wqkvt = (unsigned short*)(ws + 0 * MB);   // [3072][1024] bf16, 6MB
  unsigned short* Wot   = (unsigned short*)(ws + 6 * MB);   // 2MB
  unsigned short* W1t   = (unsigned short*)(ws + 8 * MB);   // [4096][1024], 8MB
  unsigned short* W2t   = (unsigned short*)(ws + 16 * MB);  // [1024][4096], 8MB
  float*          bqkv  = (float*)(ws + 24 * MB);           // [3072] fp32
  unsigned short* QKV   = (unsigned short*)(ws + 25 * MB);  // [4096][3072] bf16, 24MB
  unsigned short* H1    = (unsigned short*)(ws + 49 * MB);  // [4096][1024], 8MB
  unsigned short* CTX   = (unsigned short*)(ws + 49 * MB);  // aliases H1 (dead)
  unsigned short* H2    = (unsigned short*)(ws + 0 * MB);   // aliases Wqkvt+Wot (dead)
  unsigned short* FFN1  = (unsigned short*)(ws + 25 * MB);  // [4096][4096], 32MB, aliases QKV+CTX

  dim3 tb(32, 8);
  transpose_bf16<<<dim3(32, 32), tb, 0, stream>>>(Wq, Wqkvt, DMODEL, DMODEL);
  transpose_bf16<<<dim3(32, 32), tb, 0, stream>>>(Wk, Wqkvt + 1024 * 1024, DMODEL, DMODEL);
  transpose_bf16<<<dim3(32, 32), tb, 0, stream>>>(Wv, Wqkvt + 2048 * 1024, DMODEL, DMODEL);
  transpose_bf16<<<dim3(32, 32), tb, 0, stream>>>(Wo, Wot, DMODEL, DMODEL);
  transpose_bf16<<<dim3(128, 32), tb, 0, stream>>>(W1, W1t, DMODEL, DFF);
  transpose_bf16<<<dim3(32, 128), tb, 0, stream>>>(W2, W2t, DFF, DMODEL);
  concat_bias<<<12, 256, 0, stream>>>(bq, bk, bv, bqkv);

  ln_kernel<<<MROWS, 256, 0, stream>>>(x, ln1w, ln1b, H1);

  gemm_kernel<128, 0, false, true><<<dim3(24, 32), 256, 0, stream>>>(H1, Wqkvt, bqkv, nullptr, QKV, 3 * DMODEL, DMODEL);

  attn_kernel<<<BATCH * NHEADS * (LROWS / 64), 256, 0, stream>>>(QKV, CTX);

  gemm_kernel<64, 0, true, false><<<dim3(8, 64), 256, 0, stream>>>(CTX, Wot, bo, x, d_out, DMODEL, DMODEL);

  ln_kernel<<<MROWS, 256, 0, stream>>>((const float*)d_out, ln2w, ln2b, H2);

  gemm_kernel<128, 1, false, true><<<dim3(32, 32), 256, 0, stream>>>(H2, W1t, b1, nullptr, FFN1, DFF, DMODEL);

  gemm_kernel<64, 0, true, false><<<dim3(8, 64), 256, 0, stream>>>(FFN1, W2t, b2, (const float*)d_out, d_out, DMODEL, DFF);
}